// Round 5
// baseline (334.520 us; speedup 1.0000x reference)
//
#include <hip/hip_runtime.h>
#include <hip/hip_bf16.h>
#include <stdint.h>

#define B_ 8
#define T_ 2048
#define E_ 1024
#define H_ 1024
#define M_ (B_*T_)   // 16384

typedef __attribute__((ext_vector_type(8))) short bf16x8;
typedef __attribute__((ext_vector_type(4))) float f32x4;

__device__ __forceinline__ unsigned short f2bf(float f) {
  union { float f; unsigned int u; } v; v.f = f;
  unsigned int u = v.u;
  unsigned int r = u + 0x7fffu + ((u >> 16) & 1u);   // RNE (inputs finite)
  return (unsigned short)(r >> 16);
}

__device__ __forceinline__ float bf2f(unsigned short s) {
  union { unsigned int u; float f; } v; v.u = ((unsigned int)s) << 16;
  return v.f;
}

// async global->LDS, 16B per lane; LDS dest = wave-uniform base + lane*16
__device__ __forceinline__ void gload_lds16(const void* g, void* l) {
  __builtin_amdgcn_global_load_lds((const __attribute__((address_space(1))) void*)g,
                                   (__attribute__((address_space(3))) void*)l, 16, 0, 0);
}

// ---------- convert x (fp32) -> xb (bf16), 8 elems / thread ----------
__global__ void conv_x_kernel(const float* __restrict__ x,
                              unsigned short* __restrict__ xb, int n8) {
  int i = blockIdx.x * blockDim.x + threadIdx.x;
  if (i >= n8) return;
  const float4* src = (const float4*)(x + (size_t)i * 8);
  float4 a = src[0], b = src[1];
  uint4 o;
  o.x = (unsigned)f2bf(a.x) | ((unsigned)f2bf(a.y) << 16);
  o.y = (unsigned)f2bf(a.z) | ((unsigned)f2bf(a.w) << 16);
  o.z = (unsigned)f2bf(b.x) | ((unsigned)f2bf(b.y) << 16);
  o.w = (unsigned)f2bf(b.z) | ((unsigned)f2bf(b.w) << 16);
  *(uint4*)(xb + (size_t)i * 8) = o;
}

// ---------- convert + transpose W (E x H fp32) -> wT (H x E bf16) ----------
__global__ void conv_wT_kernel(const float* __restrict__ W0, const float* __restrict__ W1,
                               const float* __restrict__ W2,
                               unsigned short* __restrict__ T0, unsigned short* __restrict__ T1,
                               unsigned short* __restrict__ T2) {
  __shared__ float tile[32][33];
  const float* W = (blockIdx.z == 0) ? W0 : (blockIdx.z == 1) ? W1 : W2;
  unsigned short* Tt = (blockIdx.z == 0) ? T0 : (blockIdx.z == 1) ? T1 : T2;
  int k0 = blockIdx.x * 32;
  int n0 = blockIdx.y * 32;
  int t = threadIdx.x;
#pragma unroll
  for (int i = 0; i < 4; ++i) {
    int e = t + i * 256; int r = e >> 5, c = e & 31;
    tile[r][c] = W[(size_t)(k0 + r) * H_ + n0 + c];
  }
  __syncthreads();
#pragma unroll
  for (int i = 0; i < 4; ++i) {
    int e = t + i * 256; int r = e >> 5, c = e & 31;   // r = n-local, c = k-local
    Tt[(size_t)(n0 + r) * E_ + k0 + c] = f2bf(tile[c][r]);
  }
}

// ---------- shared GEMM core: 128x128 tile, BK=64, global_load_lds staging ----------
// Alds/Blds: linear [128][64] shorts (16KB each). acc: 4x4 f32x4 per lane.
__device__ __forceinline__ void gemm_core(const unsigned short* __restrict__ Ap, size_t strideA,
                                          const unsigned short* __restrict__ Bp, size_t strideB,
                                          int kmax, short* Alds, short* Blds,
                                          int lane, int wid, f32x4 acc[4][4]) {
  const int lo = lane & 15, hi = lane >> 4;
  const int wm = (wid >> 1) * 64, wn = (wid & 1) * 64;
  const int grow8 = wid * 8 + (lane >> 3);      // row within 32-row stripe
  const int gcol8 = (lane & 7) * 8;             // 16B column segment
  short* Al = Alds + wid * 512;                 // wave-uniform LDS base (bytes: wid*1024)
  short* Bl = Blds + wid * 512;

  for (int kb0 = 0; kb0 < kmax; kb0 += 64) {
#pragma unroll
    for (int i = 0; i < 4; ++i) {
      gload_lds16(Ap + (size_t)(i * 32 + grow8) * strideA + kb0 + gcol8, Al + i * 2048);
      gload_lds16(Bp + (size_t)(i * 32 + grow8) * strideB + kb0 + gcol8, Bl + i * 2048);
    }
    __syncthreads();
#pragma unroll
    for (int kt = 0; kt < 2; ++kt) {
      bf16x8 af[4], bfr[4];
#pragma unroll
      for (int mt = 0; mt < 4; ++mt)
        af[mt] = *(const bf16x8*)&Alds[(wm + mt * 16 + lo) * 64 + kt * 32 + hi * 8];
#pragma unroll
      for (int nt = 0; nt < 4; ++nt)
        bfr[nt] = *(const bf16x8*)&Blds[(wn + nt * 16 + lo) * 64 + kt * 32 + hi * 8];
#pragma unroll
      for (int mt = 0; mt < 4; ++mt)
#pragma unroll
        for (int nt = 0; nt < 4; ++nt)
          acc[mt][nt] = __builtin_amdgcn_mfma_f32_16x16x32_bf16(af[mt], bfr[nt], acc[mt][nt], 0, 0, 0);
    }
    __syncthreads();
  }
}

// ---------- fused QKV GEMM: out = xb @ wT^T + bias ----------
__global__ __launch_bounds__(256)
void gemm_qkv_kernel(const unsigned short* __restrict__ xb,
                     const unsigned short* __restrict__ wqT, const unsigned short* __restrict__ wkT,
                     const unsigned short* __restrict__ wvT,
                     const float* __restrict__ bq, const float* __restrict__ bk,
                     const float* __restrict__ bv,
                     unsigned short* __restrict__ qb, unsigned short* __restrict__ kb,
                     unsigned short* __restrict__ vb) {
  __shared__ short Alds[128 * 64];
  __shared__ short Blds[128 * 64];
  int which = blockIdx.y >> 3;
  int ncol0 = (blockIdx.y & 7) * 128;
  const unsigned short* Bt = (which == 0) ? wqT : (which == 1) ? wkT : wvT;
  const float* bias = (which == 0) ? bq : (which == 1) ? bk : bv;
  unsigned short* outp = (which == 0) ? qb : (which == 1) ? kb : vb;
  int m0 = blockIdx.x * 128;
  int tid = threadIdx.x, lane = tid & 63, wid = tid >> 6;
  int wm = (wid >> 1) * 64, wn = (wid & 1) * 64;

  f32x4 acc[4][4];
#pragma unroll
  for (int i = 0; i < 4; ++i)
#pragma unroll
    for (int j = 0; j < 4; ++j)
#pragma unroll
      for (int r = 0; r < 4; ++r) acc[i][j][r] = 0.f;

  gemm_core(xb + (size_t)m0 * E_, E_, Bt + (size_t)ncol0 * E_, E_, E_,
            Alds, Blds, lane, wid, acc);

  if (which == 2) {
    // transposed write: vT[d = gcol][m = grow..grow+3], 8B packed
#pragma unroll
    for (int nt = 0; nt < 4; ++nt) {
      int gcol = ncol0 + wn + nt * 16 + (lane & 15);
      float bb = bias[gcol];
#pragma unroll
      for (int mt = 0; mt < 4; ++mt) {
        int grow = m0 + wm + mt * 16 + (lane >> 4) * 4;
        ushort4 o;
        o.x = f2bf(acc[mt][nt][0] + bb);
        o.y = f2bf(acc[mt][nt][1] + bb);
        o.z = f2bf(acc[mt][nt][2] + bb);
        o.w = f2bf(acc[mt][nt][3] + bb);
        *(ushort4*)(outp + (size_t)gcol * M_ + grow) = o;
      }
    }
  } else {
#pragma unroll
    for (int nt = 0; nt < 4; ++nt) {
      int gcol = ncol0 + wn + nt * 16 + (lane & 15);
      float bb = bias[gcol];
#pragma unroll
      for (int mt = 0; mt < 4; ++mt) {
        int grow = m0 + wm + mt * 16 + (lane >> 4) * 4;
#pragma unroll
        for (int r = 0; r < 4; ++r)
          outp[(size_t)(grow + r) * H_ + gcol] = f2bf(acc[mt][nt][r] + bb);
      }
    }
  }
}

// ---------- S = (Q K^T) * scale, causal lower-tri 128x128 tiles, bf16 out ----------
__global__ __launch_bounds__(256)
void sgemm_kernel(const unsigned short* __restrict__ qb, const unsigned short* __restrict__ kb,
                  unsigned short* __restrict__ S) {
  __shared__ short Alds[128 * 64];
  __shared__ short Blds[128 * 64];
  int id = blockIdx.x;
  int b = id & 7, t = id >> 3;            // batch-fastest: same batch -> same XCD
  int mb = 0;
  while ((mb + 1) * (mb + 2) / 2 <= t) ++mb;
  int nb = t - mb * (mb + 1) / 2;         // nb <= mb (lower triangle)
  const size_t bT = (size_t)b * T_;
  int tid = threadIdx.x, lane = tid & 63, wid = tid >> 6;
  int wm = (wid >> 1) * 64, wn = (wid & 1) * 64;

  f32x4 acc[4][4];
#pragma unroll
  for (int i = 0; i < 4; ++i)
#pragma unroll
    for (int j = 0; j < 4; ++j)
#pragma unroll
      for (int r = 0; r < 4; ++r) acc[i][j][r] = 0.f;

  gemm_core(qb + (bT + mb * 128) * (size_t)H_, H_,
            kb + (bT + nb * 128) * (size_t)H_, H_, H_,
            Alds, Blds, lane, wid, acc);

#pragma unroll
  for (int nt = 0; nt < 4; ++nt) {
    int gcol = nb * 128 + wn + nt * 16 + (lane & 15);
#pragma unroll
    for (int mt = 0; mt < 4; ++mt) {
      int grow = mb * 128 + wm + mt * 16 + (lane >> 4) * 4;
#pragma unroll
      for (int r = 0; r < 4; ++r)
        S[(bT + grow + r) * (size_t)T_ + gcol] = f2bf(acc[mt][nt][r] * 0.03125f);
    }
  }
}

// ---------- in-place causal row softmax: S(bf16 scores) -> P(bf16 probs) ----------
// one wave per row; lane covers 32 cols as 4 x bf16x8 strided segments
__global__ __launch_bounds__(256)
void smax_kernel(unsigned short* __restrict__ S) {
  int id = blockIdx.x;
  int b = id & 7, rb = id >> 3;                 // rb 0..511
  int w = threadIdx.x >> 6, lane = threadIdx.x & 63;
  int row = rb * 4 + w;
  unsigned short* rp = S + ((size_t)b * T_ + row) * T_;

  bf16x8 d[4];
#pragma unroll
  for (int j = 0; j < 4; ++j)
    d[j] = *(const bf16x8*)(rp + j * 512 + lane * 8);

  float v[32];
  float mx = -1e30f;
#pragma unroll
  for (int j = 0; j < 4; ++j)
#pragma unroll
    for (int e = 0; e < 8; ++e) {
      int col = j * 512 + lane * 8 + e;
      float f = bf2f((unsigned short)d[j][e]);
      f = (col <= row) ? f : -1e30f;
      v[j * 8 + e] = f;
      mx = fmaxf(mx, f);
    }
#pragma unroll
  for (int msk = 1; msk <= 32; msk <<= 1) mx = fmaxf(mx, __shfl_xor(mx, msk));

  float s = 0.f;
#pragma unroll
  for (int i = 0; i < 32; ++i) {
    v[i] = __expf(v[i] - mx);                   // masked: exp(-1e30 - mx) underflows to 0
    s += v[i];
  }
#pragma unroll
  for (int msk = 1; msk <= 32; msk <<= 1) s += __shfl_xor(s, msk);
  float inv = 1.0f / s;

#pragma unroll
  for (int j = 0; j < 4; ++j) {
    bf16x8 o;
#pragma unroll
    for (int e = 0; e < 8; ++e) o[e] = (short)f2bf(v[j * 8 + e] * inv);
    *(bf16x8*)(rp + j * 512 + lane * 8) = o;
  }
}

// ---------- O = P V, causal (K-range = (mb+1)*128), fp32 out ----------
__global__ __launch_bounds__(256)
void pv_kernel(const unsigned short* __restrict__ P, const unsigned short* __restrict__ vT,
               float* __restrict__ out) {
  __shared__ short Alds[128 * 64];
  __shared__ short Blds[128 * 64];
  int id = blockIdx.x;
  int b = id & 7, u = id >> 3;
  int mb = 15 - (u >> 3);                  // biggest K-range first (load balance)
  int nb = u & 7;                          // d-block 0..7
  const size_t bT = (size_t)b * T_;
  int tid = threadIdx.x, lane = tid & 63, wid = tid >> 6;
  int wm = (wid >> 1) * 64, wn = (wid & 1) * 64;

  f32x4 acc[4][4];
#pragma unroll
  for (int i = 0; i < 4; ++i)
#pragma unroll
    for (int j = 0; j < 4; ++j)
#pragma unroll
      for (int r = 0; r < 4; ++r) acc[i][j][r] = 0.f;

  gemm_core(P + (bT + mb * 128) * (size_t)T_, T_,
            vT + (size_t)(nb * 128) * M_ + bT, M_,
            (mb + 1) * 128, Alds, Blds, lane, wid, acc);

#pragma unroll
  for (int nt = 0; nt < 4; ++nt) {
    int gcol = nb * 128 + wn + nt * 16 + (lane & 15);
#pragma unroll
    for (int mt = 0; mt < 4; ++mt) {
      int grow = mb * 128 + wm + mt * 16 + (lane >> 4) * 4;
#pragma unroll
      for (int r = 0; r < 4; ++r)
        out[(bT + grow + r) * (size_t)H_ + gcol] = acc[mt][nt][r];
    }
  }
}

extern "C" void kernel_launch(void* const* d_in, const int* in_sizes, int n_in,
                              void* d_out, int out_size, void* d_ws, size_t ws_size,
                              hipStream_t stream) {
  const float* x  = (const float*)d_in[0];
  const float* Wq = (const float*)d_in[1];
  const float* bq = (const float*)d_in[2];
  const float* Wk = (const float*)d_in[3];
  const float* bk = (const float*)d_in[4];
  const float* Wv = (const float*)d_in[5];
  const float* bv = (const float*)d_in[6];
  float* out = (float*)d_out;

  unsigned short* ws = (unsigned short*)d_ws;
  unsigned short* xb  = ws;                              // M x E bf16      (32MB)
  unsigned short* wqT = xb  + (size_t)M_ * E_;           // H x E bf16
  unsigned short* wkT = wqT + (size_t)E_ * H_;
  unsigned short* wvT = wkT + (size_t)E_ * H_;
  unsigned short* qb  = wvT + (size_t)E_ * H_;           // M x H bf16      (32MB)
  unsigned short* kbp = qb  + (size_t)M_ * H_;           // M x H bf16
  unsigned short* vTp = kbp + (size_t)M_ * H_;           // H x M bf16 (V transposed)
  unsigned short* Sp  = vTp + (size_t)M_ * H_;           // B x T x T bf16  (67MB) S, then P in-place

  conv_x_kernel<<<(M_ * E_ / 8 + 255) / 256, 256, 0, stream>>>(x, xb, M_ * E_ / 8);
  conv_wT_kernel<<<dim3(32, 32, 3), 256, 0, stream>>>(Wq, Wk, Wv, wqT, wkT, wvT);
  gemm_qkv_kernel<<<dim3(128, 24), 256, 0, stream>>>(xb, wqT, wkT, wvT, bq, bk, bv, qb, kbp, vTp);
  sgemm_kernel<<<dim3(136 * 8), 256, 0, stream>>>(qb, kbp, Sp);
  smax_kernel<<<dim3(512 * 8), 256, 0, stream>>>(Sp);
  pv_kernel<<<dim3(128 * 8), 256, 0, stream>>>(Sp, vTp, out);
}

// Round 6
// 297.869 us; speedup vs baseline: 1.1230x; 1.1230x over previous
//
#include <hip/hip_runtime.h>
#include <hip/hip_bf16.h>
#include <stdint.h>

#define B_ 8
#define T_ 2048
#define E_ 1024
#define H_ 1024
#define M_ (B_*T_)   // 16384

typedef __attribute__((ext_vector_type(8))) short bf16x8;
typedef __attribute__((ext_vector_type(4))) float f32x4;

__device__ __forceinline__ unsigned short f2bf(float f) {
  union { float f; unsigned int u; } v; v.f = f;
  unsigned int u = v.u;
  unsigned int r = u + 0x7fffu + ((u >> 16) & 1u);   // RNE (inputs finite)
  return (unsigned short)(r >> 16);
}

__device__ __forceinline__ float bf2f(unsigned short s) {
  union { unsigned int u; float f; } v; v.u = ((unsigned int)s) << 16;
  return v.f;
}

// async global->LDS, 16B per lane; LDS dest = wave-uniform base + lane*16
__device__ __forceinline__ void gload_lds16(const void* g, void* l) {
  __builtin_amdgcn_global_load_lds((const __attribute__((address_space(1))) void*)g,
                                   (__attribute__((address_space(3))) void*)l, 16, 0, 0);
}

// swizzled LDS fragment read: row R (stride 128B), 16B-granule G, XOR (R&7) into granule bits
__device__ __forceinline__ bf16x8 lds_read_swz(const short* base, int R, int G) {
  return *(const bf16x8*)((const char*)base + (((R << 7) + (G << 4)) ^ ((R & 7) << 4)));
}

// ---------- convert x (fp32) -> xb (bf16), 8 elems / thread ----------
__global__ void conv_x_kernel(const float* __restrict__ x,
                              unsigned short* __restrict__ xb, int n8) {
  int i = blockIdx.x * blockDim.x + threadIdx.x;
  if (i >= n8) return;
  const float4* src = (const float4*)(x + (size_t)i * 8);
  float4 a = src[0], b = src[1];
  uint4 o;
  o.x = (unsigned)f2bf(a.x) | ((unsigned)f2bf(a.y) << 16);
  o.y = (unsigned)f2bf(a.z) | ((unsigned)f2bf(a.w) << 16);
  o.z = (unsigned)f2bf(b.x) | ((unsigned)f2bf(b.y) << 16);
  o.w = (unsigned)f2bf(b.z) | ((unsigned)f2bf(b.w) << 16);
  *(uint4*)(xb + (size_t)i * 8) = o;
}

// ---------- convert + transpose W (E x H fp32) -> wT (H x E bf16) ----------
__global__ void conv_wT_kernel(const float* __restrict__ W0, const float* __restrict__ W1,
                               const float* __restrict__ W2,
                               unsigned short* __restrict__ T0, unsigned short* __restrict__ T1,
                               unsigned short* __restrict__ T2) {
  __shared__ float tile[32][33];
  const float* W = (blockIdx.z == 0) ? W0 : (blockIdx.z == 1) ? W1 : W2;
  unsigned short* Tt = (blockIdx.z == 0) ? T0 : (blockIdx.z == 1) ? T1 : T2;
  int k0 = blockIdx.x * 32;
  int n0 = blockIdx.y * 32;
  int t = threadIdx.x;
#pragma unroll
  for (int i = 0; i < 4; ++i) {
    int e = t + i * 256; int r = e >> 5, c = e & 31;
    tile[r][c] = W[(size_t)(k0 + r) * H_ + n0 + c];
  }
  __syncthreads();
#pragma unroll
  for (int i = 0; i < 4; ++i) {
    int e = t + i * 256; int r = e >> 5, c = e & 31;   // r = n-local, c = k-local
    Tt[(size_t)(n0 + r) * E_ + k0 + c] = f2bf(tile[c][r]);
  }
}

// ---------- shared GEMM core: 128x128 tile, BK=64, global_load_lds staging ----------
// LDS linear [128][64] shorts; swizzle realized by pre-swizzled GLOBAL source
// (lane staging LDS granule gg of row r fetches global granule gg^(r&7)),
// reads undo it with the same XOR. (m173/m201 both-sides pattern.)
__device__ __forceinline__ void gemm_core(const unsigned short* __restrict__ Ap, size_t strideA,
                                          const unsigned short* __restrict__ Bp, size_t strideB,
                                          int kmax, short* Alds, short* Blds,
                                          int lane, int wid, f32x4 acc[4][4]) {
  const int lo = lane & 15, hi = lane >> 4;
  const int wm = (wid >> 1) * 64, wn = (wid & 1) * 64;
  const int srow = wid * 8 + (lane >> 3);                 // row within 32-row stripe
  const int scol = ((lane & 7) ^ (srow & 7)) * 8;         // pre-swizzled 16B col segment (shorts)
  short* Al = Alds + wid * 512;                           // wave-uniform LDS base (bytes: wid*1024)
  short* Bl = Blds + wid * 512;

  for (int kb0 = 0; kb0 < kmax; kb0 += 64) {
#pragma unroll
    for (int i = 0; i < 4; ++i) {
      gload_lds16(Ap + (size_t)(i * 32 + srow) * strideA + kb0 + scol, Al + i * 2048);
      gload_lds16(Bp + (size_t)(i * 32 + srow) * strideB + kb0 + scol, Bl + i * 2048);
    }
    __syncthreads();
#pragma unroll
    for (int kt = 0; kt < 2; ++kt) {
      bf16x8 af[4], bfr[4];
#pragma unroll
      for (int mt = 0; mt < 4; ++mt)
        af[mt] = lds_read_swz(Alds, wm + mt * 16 + lo, kt * 4 + hi);
#pragma unroll
      for (int nt = 0; nt < 4; ++nt)
        bfr[nt] = lds_read_swz(Blds, wn + nt * 16 + lo, kt * 4 + hi);
#pragma unroll
      for (int mt = 0; mt < 4; ++mt)
#pragma unroll
        for (int nt = 0; nt < 4; ++nt)
          acc[mt][nt] = __builtin_amdgcn_mfma_f32_16x16x32_bf16(af[mt], bfr[nt], acc[mt][nt], 0, 0, 0);
    }
    __syncthreads();
  }
}

// ---------- fused QKV GEMM: out = xb @ wT^T + bias ----------
__global__ __launch_bounds__(256)
void gemm_qkv_kernel(const unsigned short* __restrict__ xb,
                     const unsigned short* __restrict__ wqT, const unsigned short* __restrict__ wkT,
                     const unsigned short* __restrict__ wvT,
                     const float* __restrict__ bq, const float* __restrict__ bk,
                     const float* __restrict__ bv,
                     unsigned short* __restrict__ qb, unsigned short* __restrict__ kb,
                     unsigned short* __restrict__ vb) {
  __shared__ short Alds[128 * 64];
  __shared__ short Blds[128 * 64];
  int which = blockIdx.y >> 3;
  int ncol0 = (blockIdx.y & 7) * 128;
  const unsigned short* Bt = (which == 0) ? wqT : (which == 1) ? wkT : wvT;
  const float* bias = (which == 0) ? bq : (which == 1) ? bk : bv;
  unsigned short* outp = (which == 0) ? qb : (which == 1) ? kb : vb;
  int m0 = blockIdx.x * 128;
  int tid = threadIdx.x, lane = tid & 63, wid = tid >> 6;
  int wm = (wid >> 1) * 64, wn = (wid & 1) * 64;

  f32x4 acc[4][4];
#pragma unroll
  for (int i = 0; i < 4; ++i)
#pragma unroll
    for (int j = 0; j < 4; ++j)
#pragma unroll
      for (int r = 0; r < 4; ++r) acc[i][j][r] = 0.f;

  gemm_core(xb + (size_t)m0 * E_, E_, Bt + (size_t)ncol0 * E_, E_, E_,
            Alds, Blds, lane, wid, acc);

  if (which == 2) {
    // transposed write: vT[d = gcol][m = grow..grow+3], 8B packed
#pragma unroll
    for (int nt = 0; nt < 4; ++nt) {
      int gcol = ncol0 + wn + nt * 16 + (lane & 15);
      float bb = bias[gcol];
#pragma unroll
      for (int mt = 0; mt < 4; ++mt) {
        int grow = m0 + wm + mt * 16 + (lane >> 4) * 4;
        ushort4 o;
        o.x = f2bf(acc[mt][nt][0] + bb);
        o.y = f2bf(acc[mt][nt][1] + bb);
        o.z = f2bf(acc[mt][nt][2] + bb);
        o.w = f2bf(acc[mt][nt][3] + bb);
        *(ushort4*)(outp + (size_t)gcol * M_ + grow) = o;
      }
    }
  } else {
#pragma unroll
    for (int nt = 0; nt < 4; ++nt) {
      int gcol = ncol0 + wn + nt * 16 + (lane & 15);
      float bb = bias[gcol];
#pragma unroll
      for (int mt = 0; mt < 4; ++mt) {
        int grow = m0 + wm + mt * 16 + (lane >> 4) * 4;
#pragma unroll
        for (int r = 0; r < 4; ++r)
          outp[(size_t)(grow + r) * H_ + gcol] = f2bf(acc[mt][nt][r] + bb);
      }
    }
  }
}

// ---------- S = (Q K^T) * scale, causal lower-tri 128x128 tiles, bf16 out ----------
__global__ __launch_bounds__(256)
void sgemm_kernel(const unsigned short* __restrict__ qb, const unsigned short* __restrict__ kb,
                  unsigned short* __restrict__ S) {
  __shared__ short Alds[128 * 64];
  __shared__ short Blds[128 * 64];
  int id = blockIdx.x;
  int b = id & 7, t = id >> 3;            // batch-fastest: same batch -> same XCD
  int mb = 0;
  while ((mb + 1) * (mb + 2) / 2 <= t) ++mb;
  int nb = t - mb * (mb + 1) / 2;         // nb <= mb (lower triangle)
  const size_t bT = (size_t)b * T_;
  int tid = threadIdx.x, lane = tid & 63, wid = tid >> 6;
  int wm = (wid >> 1) * 64, wn = (wid & 1) * 64;

  f32x4 acc[4][4];
#pragma unroll
  for (int i = 0; i < 4; ++i)
#pragma unroll
    for (int j = 0; j < 4; ++j)
#pragma unroll
      for (int r = 0; r < 4; ++r) acc[i][j][r] = 0.f;

  gemm_core(qb + (bT + mb * 128) * (size_t)H_, H_,
            kb + (bT + nb * 128) * (size_t)H_, H_, H_,
            Alds, Blds, lane, wid, acc);

#pragma unroll
  for (int nt = 0; nt < 4; ++nt) {
    int gcol = nb * 128 + wn + nt * 16 + (lane & 15);
#pragma unroll
    for (int mt = 0; mt < 4; ++mt) {
      int grow = mb * 128 + wm + mt * 16 + (lane >> 4) * 4;
#pragma unroll
      for (int r = 0; r < 4; ++r)
        S[(bT + grow + r) * (size_t)T_ + gcol] = f2bf(acc[mt][nt][r] * 0.03125f);
    }
  }
}

// ---------- in-place causal row softmax: S(bf16 scores) -> P(bf16 probs) ----------
// one wave per row; lane covers 32 cols as 4 x bf16x8 strided segments
__global__ __launch_bounds__(256)
void smax_kernel(unsigned short* __restrict__ S) {
  int id = blockIdx.x;
  int b = id & 7, rb = id >> 3;                 // rb 0..511
  int w = threadIdx.x >> 6, lane = threadIdx.x & 63;
  int row = rb * 4 + w;
  unsigned short* rp = S + ((size_t)b * T_ + row) * T_;

  bf16x8 d[4];
#pragma unroll
  for (int j = 0; j < 4; ++j)
    d[j] = *(const bf16x8*)(rp + j * 512 + lane * 8);

  float v[32];
  float mx = -1e30f;
#pragma unroll
  for (int j = 0; j < 4; ++j)
#pragma unroll
    for (int e = 0; e < 8; ++e) {
      int col = j * 512 + lane * 8 + e;
      float f = bf2f((unsigned short)d[j][e]);
      f = (col <= row) ? f : -1e30f;
      v[j * 8 + e] = f;
      mx = fmaxf(mx, f);
    }
#pragma unroll
  for (int msk = 1; msk <= 32; msk <<= 1) mx = fmaxf(mx, __shfl_xor(mx, msk));

  float s = 0.f;
#pragma unroll
  for (int i = 0; i < 32; ++i) {
    v[i] = __expf(v[i] - mx);                   // masked: exp(-1e30 - mx) underflows to 0
    s += v[i];
  }
#pragma unroll
  for (int msk = 1; msk <= 32; msk <<= 1) s += __shfl_xor(s, msk);
  float inv = 1.0f / s;

#pragma unroll
  for (int j = 0; j < 4; ++j) {
    bf16x8 o;
#pragma unroll
    for (int e = 0; e < 8; ++e) o[e] = (short)f2bf(v[j * 8 + e] * inv);
    *(bf16x8*)(rp + j * 512 + lane * 8) = o;
  }
}

// ---------- O = P V, causal (K-range = (mb+1)*128), fp32 out ----------
__global__ __launch_bounds__(256)
void pv_kernel(const unsigned short* __restrict__ P, const unsigned short* __restrict__ vT,
               float* __restrict__ out) {
  __shared__ short Alds[128 * 64];
  __shared__ short Blds[128 * 64];
  int id = blockIdx.x;
  int b = id & 7, u = id >> 3;
  int mb = 15 - (u >> 3);                  // biggest K-range first (load balance)
  int nb = u & 7;                          // d-block 0..7
  const size_t bT = (size_t)b * T_;
  int tid = threadIdx.x, lane = tid & 63, wid = tid >> 6;
  int wm = (wid >> 1) * 64, wn = (wid & 1) * 64;

  f32x4 acc[4][4];
#pragma unroll
  for (int i = 0; i < 4; ++i)
#pragma unroll
    for (int j = 0; j < 4; ++j)
#pragma unroll
      for (int r = 0; r < 4; ++r) acc[i][j][r] = 0.f;

  gemm_core(P + (bT + mb * 128) * (size_t)T_, T_,
            vT + (size_t)(nb * 128) * M_ + bT, M_,
            (mb + 1) * 128, Alds, Blds, lane, wid, acc);

#pragma unroll
  for (int nt = 0; nt < 4; ++nt) {
    int gcol = nb * 128 + wn + nt * 16 + (lane & 15);
#pragma unroll
    for (int mt = 0; mt < 4; ++mt) {
      int grow = mb * 128 + wm + mt * 16 + (lane >> 4) * 4;
#pragma unroll
      for (int r = 0; r < 4; ++r)
        out[(bT + grow + r) * (size_t)H_ + gcol] = acc[mt][nt][r];
    }
  }
}

extern "C" void kernel_launch(void* const* d_in, const int* in_sizes, int n_in,
                              void* d_out, int out_size, void* d_ws, size_t ws_size,
                              hipStream_t stream) {
  const float* x  = (const float*)d_in[0];
  const float* Wq = (const float*)d_in[1];
  const float* bq = (const float*)d_in[2];
  const float* Wk = (const float*)d_in[3];
  const float* bk = (const float*)d_in[4];
  const float* Wv = (const float*)d_in[5];
  const float* bv = (const float*)d_in[6];
  float* out = (float*)d_out;

  unsigned short* ws = (unsigned short*)d_ws;
  unsigned short* xb  = ws;                              // M x E bf16      (32MB)
  unsigned short* wqT = xb  + (size_t)M_ * E_;           // H x E bf16
  unsigned short* wkT = wqT + (size_t)E_ * H_;
  unsigned short* wvT = wkT + (size_t)E_ * H_;
  unsigned short* qb  = wvT + (size_t)E_ * H_;           // M x H bf16      (32MB)
  unsigned short* kbp = qb  + (size_t)M_ * H_;           // M x H bf16
  unsigned short* vTp = kbp + (size_t)M_ * H_;           // H x M bf16 (V transposed)
  unsigned short* Sp  = vTp + (size_t)M_ * H_;           // B x T x T bf16  (67MB) S, then P in-place

  conv_x_kernel<<<(M_ * E_ / 8 + 255) / 256, 256, 0, stream>>>(x, xb, M_ * E_ / 8);
  conv_wT_kernel<<<dim3(32, 32, 3), 256, 0, stream>>>(Wq, Wk, Wv, wqT, wkT, wvT);
  gemm_qkv_kernel<<<dim3(128, 24), 256, 0, stream>>>(xb, wqT, wkT, wvT, bq, bk, bv, qb, kbp, vTp);
  sgemm_kernel<<<dim3(136 * 8), 256, 0, stream>>>(qb, kbp, Sp);
  smax_kernel<<<dim3(512 * 8), 256, 0, stream>>>(Sp);
  pv_kernel<<<dim3(128 * 8), 256, 0, stream>>>(Sp, vTp, out);
}

// Round 7
// 276.833 us; speedup vs baseline: 1.2084x; 1.0760x over previous
//
#include <hip/hip_runtime.h>
#include <hip/hip_bf16.h>
#include <stdint.h>

#define B_ 8
#define T_ 2048
#define E_ 1024
#define H_ 1024
#define M_ (B_*T_)   // 16384

typedef __attribute__((ext_vector_type(8))) short bf16x8;
typedef __attribute__((ext_vector_type(4))) float f32x4;

__device__ __forceinline__ unsigned short f2bf(float f) {
  union { float f; unsigned int u; } v; v.f = f;
  unsigned int u = v.u;
  unsigned int r = u + 0x7fffu + ((u >> 16) & 1u);   // RNE (inputs finite)
  return (unsigned short)(r >> 16);
}

__device__ __forceinline__ float bf2f(unsigned short s) {
  union { unsigned int u; float f; } v; v.u = ((unsigned int)s) << 16;
  return v.f;
}

// async global->LDS, 16B per lane; LDS dest = wave-uniform base + lane*16
__device__ __forceinline__ void gload_lds16(const void* g, void* l) {
  __builtin_amdgcn_global_load_lds((const __attribute__((address_space(1))) void*)g,
                                   (__attribute__((address_space(3))) void*)l, 16, 0, 0);
}

// swizzled LDS fragment read: row R (stride 128B), 16B-granule G, XOR (R&7) into granule bits
__device__ __forceinline__ bf16x8 lds_read_swz(const short* base, int R, int G) {
  return *(const bf16x8*)((const char*)base + (((R << 7) + (G << 4)) ^ ((R & 7) << 4)));
}

#define MEMFENCE asm volatile("" ::: "memory")
#define BARRIER() do { MEMFENCE; __builtin_amdgcn_s_barrier(); MEMFENCE; } while (0)

// ---------- convert x (fp32) -> xb (bf16), 8 elems / thread ----------
__global__ void conv_x_kernel(const float* __restrict__ x,
                              unsigned short* __restrict__ xb, int n8) {
  int i = blockIdx.x * blockDim.x + threadIdx.x;
  if (i >= n8) return;
  const float4* src = (const float4*)(x + (size_t)i * 8);
  float4 a = src[0], b = src[1];
  uint4 o;
  o.x = (unsigned)f2bf(a.x) | ((unsigned)f2bf(a.y) << 16);
  o.y = (unsigned)f2bf(a.z) | ((unsigned)f2bf(a.w) << 16);
  o.z = (unsigned)f2bf(b.x) | ((unsigned)f2bf(b.y) << 16);
  o.w = (unsigned)f2bf(b.z) | ((unsigned)f2bf(b.w) << 16);
  *(uint4*)(xb + (size_t)i * 8) = o;
}

// ---------- convert + transpose W (E x H fp32) -> wT (H x E bf16) ----------
__global__ void conv_wT_kernel(const float* __restrict__ W0, const float* __restrict__ W1,
                               const float* __restrict__ W2,
                               unsigned short* __restrict__ T0, unsigned short* __restrict__ T1,
                               unsigned short* __restrict__ T2) {
  __shared__ float tile[32][33];
  const float* W = (blockIdx.z == 0) ? W0 : (blockIdx.z == 1) ? W1 : W2;
  unsigned short* Tt = (blockIdx.z == 0) ? T0 : (blockIdx.z == 1) ? T1 : T2;
  int k0 = blockIdx.x * 32;
  int n0 = blockIdx.y * 32;
  int t = threadIdx.x;
#pragma unroll
  for (int i = 0; i < 4; ++i) {
    int e = t + i * 256; int r = e >> 5, c = e & 31;
    tile[r][c] = W[(size_t)(k0 + r) * H_ + n0 + c];
  }
  __syncthreads();
#pragma unroll
  for (int i = 0; i < 4; ++i) {
    int e = t + i * 256; int r = e >> 5, c = e & 31;   // r = n-local, c = k-local
    Tt[(size_t)(n0 + r) * E_ + k0 + c] = f2bf(tile[c][r]);
  }
}

// ================== 256x256 8-phase GEMM (QKV projection) ==================
// 8 waves (2M x 4N), BK=64, double-buffered 128KB LDS, counted vmcnt(6),
// raw s_barrier, setprio around MFMA clusters. Stage swizzle = pre-swizzled
// global source + XOR read (R6-proven, 0 bank conflicts).

// part: 0=A rows 0-127, 1=A rows 128-255, 2=B rows 0-127, 3=B rows 128-255
__device__ __forceinline__ void stage_part(const unsigned short* Ap, size_t sA,
                                           const unsigned short* Bp, size_t sB,
                                           short* Alds, short* Blds, int V, int part, int tid) {
  const int srow = tid >> 3;                      // 0..63
  const int sg = ((tid & 7) ^ (srow & 7)) * 8;    // pre-swizzled granule (shorts)
  const int w = tid >> 6;
  const unsigned short* g; short* l; size_t gs;
  if (part == 0)      { g = Ap;                    l = Alds;            gs = sA; }
  else if (part == 1) { g = Ap + (size_t)128 * sA; l = Alds + 128 * 64; gs = sA; }
  else if (part == 2) { g = Bp;                    l = Blds;            gs = sB; }
  else                { g = Bp + (size_t)128 * sB; l = Blds + 128 * 64; gs = sB; }
  const unsigned short* gr = g + (size_t)V * 64 + (size_t)srow * gs + sg;
#pragma unroll
  for (int r = 0; r < 2; ++r)
    gload_lds16(gr + (size_t)(r * 64) * gs, l + (r * 64 + w * 8) * 64);
}

__global__ __launch_bounds__(512, 2)
void gemm_qkv256_kernel(const unsigned short* __restrict__ xb,
                        const unsigned short* __restrict__ wqT, const unsigned short* __restrict__ wkT,
                        const unsigned short* __restrict__ wvT,
                        const float* __restrict__ bq, const float* __restrict__ bk,
                        const float* __restrict__ bv,
                        unsigned short* __restrict__ qb, unsigned short* __restrict__ kb,
                        unsigned short* __restrict__ vb) {
  __shared__ short As0[256 * 64], As1[256 * 64], Bs0[256 * 64], Bs1[256 * 64];
  const int which = blockIdx.y >> 2;
  const int ncol0 = (blockIdx.y & 3) * 256;
  const unsigned short* Bt = (which == 0) ? wqT : (which == 1) ? wkT : wvT;
  const float* bias = (which == 0) ? bq : (which == 1) ? bk : bv;
  unsigned short* outp = (which == 0) ? qb : (which == 1) ? kb : vb;
  const int m0 = blockIdx.x * 256;
  const unsigned short* Ap = xb + (size_t)m0 * E_;
  const unsigned short* Bp = Bt + (size_t)ncol0 * E_;
  const int NT = E_ / 64;   // 16

  const int tid = threadIdx.x, lane = tid & 63, w = tid >> 6;
  const int lo = lane & 15, hi = lane >> 4;
  const int wm = (w >> 2) * 128, wn = (w & 3) * 64;

  f32x4 acc[8][4];
#pragma unroll
  for (int i = 0; i < 8; ++i)
#pragma unroll
    for (int j = 0; j < 4; ++j)
#pragma unroll
      for (int r = 0; r < 4; ++r) acc[i][j][r] = 0.f;

#define ST(V, P) do { if ((V) < NT) stage_part(Ap, E_, Bp, E_, ((V) & 1) ? As1 : As0, ((V) & 1) ? Bs1 : Bs0, (V), (P), tid); } while (0)

  // ---- prologue: tile0 all 4 halves, stagger, tile1 {B-hi, A-lo, A-hi} ----
  ST(0, 0); ST(0, 1); ST(0, 2); ST(0, 3);
  asm volatile("s_waitcnt vmcnt(4)" ::: "memory");
  ST(1, 3); ST(1, 0); ST(1, 1);
  asm volatile("s_waitcnt vmcnt(6)" ::: "memory");
  BARRIER();

  bf16x8 a[4][2], b0[2][2], b1[2][2];
  for (int U = 0; U < NT; ++U) {
    const short* Ac = (U & 1) ? As1 : As0;
    const short* Bc = (U & 1) ? Bs1 : Bs0;
    // ---------- phase 1: reads A-M0 + B-N0, stage (U+1).B-lo, MFMA (M0,N0) ----------
#pragma unroll
    for (int mt = 0; mt < 4; ++mt)
#pragma unroll
      for (int kt = 0; kt < 2; ++kt)
        a[mt][kt] = lds_read_swz(Ac, wm + mt * 16 + lo, kt * 4 + hi);
#pragma unroll
    for (int nt = 0; nt < 2; ++nt)
#pragma unroll
      for (int kt = 0; kt < 2; ++kt)
        b0[nt][kt] = lds_read_swz(Bc, wn + nt * 16 + lo, kt * 4 + hi);
    ST(U + 1, 2);
    BARRIER();
    __builtin_amdgcn_s_setprio(1);
#pragma unroll
    for (int mt = 0; mt < 4; ++mt)
#pragma unroll
      for (int nt = 0; nt < 2; ++nt)
#pragma unroll
        for (int kt = 0; kt < 2; ++kt)
          acc[mt][nt] = __builtin_amdgcn_mfma_f32_16x16x32_bf16(a[mt][kt], b0[nt][kt], acc[mt][nt], 0, 0, 0);
    __builtin_amdgcn_s_setprio(0);
    BARRIER();
    // ---------- phase 2: reads B-N1, MFMA (M0,N1) ----------
#pragma unroll
    for (int nt = 0; nt < 2; ++nt)
#pragma unroll
      for (int kt = 0; kt < 2; ++kt)
        b1[nt][kt] = lds_read_swz(Bc, wn + 32 + nt * 16 + lo, kt * 4 + hi);
    BARRIER();
    __builtin_amdgcn_s_setprio(1);
#pragma unroll
    for (int mt = 0; mt < 4; ++mt)
#pragma unroll
      for (int nt = 0; nt < 2; ++nt)
#pragma unroll
        for (int kt = 0; kt < 2; ++kt)
          acc[mt][2 + nt] = __builtin_amdgcn_mfma_f32_16x16x32_bf16(a[mt][kt], b1[nt][kt], acc[mt][2 + nt], 0, 0, 0);
    __builtin_amdgcn_s_setprio(0);
    BARRIER();
    // ---------- phase 3: reads A-M1, stage (U+2).B-hi, MFMA (M1,N0) ----------
#pragma unroll
    for (int mt = 0; mt < 4; ++mt)
#pragma unroll
      for (int kt = 0; kt < 2; ++kt)
        a[mt][kt] = lds_read_swz(Ac, wm + 64 + mt * 16 + lo, kt * 4 + hi);
    ST(U + 2, 3);
    BARRIER();
    __builtin_amdgcn_s_setprio(1);
#pragma unroll
    for (int mt = 0; mt < 4; ++mt)
#pragma unroll
      for (int nt = 0; nt < 2; ++nt)
#pragma unroll
        for (int kt = 0; kt < 2; ++kt)
          acc[4 + mt][nt] = __builtin_amdgcn_mfma_f32_16x16x32_bf16(a[mt][kt], b0[nt][kt], acc[4 + mt][nt], 0, 0, 0);
    __builtin_amdgcn_s_setprio(0);
    BARRIER();
    // ---------- phase 4: stage (U+2).A-lo + A-hi, MFMA (M1,N1), boundary vmcnt ----------
    ST(U + 2, 0);
    ST(U + 2, 1);
    BARRIER();
    __builtin_amdgcn_s_setprio(1);
#pragma unroll
    for (int mt = 0; mt < 4; ++mt)
#pragma unroll
      for (int nt = 0; nt < 2; ++nt)
#pragma unroll
        for (int kt = 0; kt < 2; ++kt)
          acc[4 + mt][2 + nt] = __builtin_amdgcn_mfma_f32_16x16x32_bf16(a[mt][kt], b1[nt][kt], acc[4 + mt][2 + nt], 0, 0, 0);
    __builtin_amdgcn_s_setprio(0);
    if (U + 2 < NT) asm volatile("s_waitcnt vmcnt(6)" ::: "memory");
    else            asm volatile("s_waitcnt vmcnt(0)" ::: "memory");
    BARRIER();
  }
#undef ST

  // ---------- epilogue ----------
  if (which == 2) {
    // transposed write: vT[d = gcol][m], 8B packed
#pragma unroll
    for (int j = 0; j < 4; ++j) {
      int gcol = ncol0 + wn + (j >> 1) * 32 + (j & 1) * 16 + lo;
      float bb = bias[gcol];
#pragma unroll
      for (int i = 0; i < 8; ++i) {
        int grow = m0 + wm + (i >> 2) * 64 + (i & 3) * 16 + hi * 4;
        ushort4 o;
        o.x = f2bf(acc[i][j][0] + bb);
        o.y = f2bf(acc[i][j][1] + bb);
        o.z = f2bf(acc[i][j][2] + bb);
        o.w = f2bf(acc[i][j][3] + bb);
        *(ushort4*)(outp + (size_t)gcol * M_ + grow) = o;
      }
    }
  } else {
#pragma unroll
    for (int j = 0; j < 4; ++j) {
      int gcol = ncol0 + wn + (j >> 1) * 32 + (j & 1) * 16 + lo;
      float bb = bias[gcol];
#pragma unroll
      for (int i = 0; i < 8; ++i) {
        int grow = m0 + wm + (i >> 2) * 64 + (i & 3) * 16 + hi * 4;
#pragma unroll
        for (int r = 0; r < 4; ++r)
          outp[(size_t)(grow + r) * H_ + gcol] = f2bf(acc[i][j][r] + bb);
      }
    }
  }
}

// ---------- shared 128x128 GEMM core (R6-proven) for sgemm/pv ----------
__device__ __forceinline__ void gemm_core(const unsigned short* __restrict__ Ap, size_t strideA,
                                          const unsigned short* __restrict__ Bp, size_t strideB,
                                          int kmax, short* Alds, short* Blds,
                                          int lane, int wid, f32x4 acc[4][4]) {
  const int lo = lane & 15, hi = lane >> 4;
  const int wm = (wid >> 1) * 64, wn = (wid & 1) * 64;
  const int srow = wid * 8 + (lane >> 3);
  const int scol = ((lane & 7) ^ (srow & 7)) * 8;
  short* Al = Alds + wid * 512;
  short* Bl = Blds + wid * 512;

  for (int kb0 = 0; kb0 < kmax; kb0 += 64) {
#pragma unroll
    for (int i = 0; i < 4; ++i) {
      gload_lds16(Ap + (size_t)(i * 32 + srow) * strideA + kb0 + scol, Al + i * 2048);
      gload_lds16(Bp + (size_t)(i * 32 + srow) * strideB + kb0 + scol, Bl + i * 2048);
    }
    __syncthreads();
#pragma unroll
    for (int kt = 0; kt < 2; ++kt) {
      bf16x8 af[4], bfr[4];
#pragma unroll
      for (int mt = 0; mt < 4; ++mt)
        af[mt] = lds_read_swz(Alds, wm + mt * 16 + lo, kt * 4 + hi);
#pragma unroll
      for (int nt = 0; nt < 4; ++nt)
        bfr[nt] = lds_read_swz(Blds, wn + nt * 16 + lo, kt * 4 + hi);
#pragma unroll
      for (int mt = 0; mt < 4; ++mt)
#pragma unroll
        for (int nt = 0; nt < 4; ++nt)
          acc[mt][nt] = __builtin_amdgcn_mfma_f32_16x16x32_bf16(af[mt], bfr[nt], acc[mt][nt], 0, 0, 0);
    }
    __syncthreads();
  }
}

// ---------- S = (Q K^T) * scale, causal lower-tri 128x128 tiles, bf16 out ----------
__global__ __launch_bounds__(256)
void sgemm_kernel(const unsigned short* __restrict__ qb, const unsigned short* __restrict__ kb,
                  unsigned short* __restrict__ S) {
  __shared__ short Alds[128 * 64];
  __shared__ short Blds[128 * 64];
  int id = blockIdx.x;
  int b = id & 7, t = id >> 3;            // batch-fastest: same batch -> same XCD
  int mb = 0;
  while ((mb + 1) * (mb + 2) / 2 <= t) ++mb;
  int nb = t - mb * (mb + 1) / 2;         // nb <= mb (lower triangle)
  const size_t bT = (size_t)b * T_;
  int tid = threadIdx.x, lane = tid & 63, wid = tid >> 6;
  int wm = (wid >> 1) * 64, wn = (wid & 1) * 64;

  f32x4 acc[4][4];
#pragma unroll
  for (int i = 0; i < 4; ++i)
#pragma unroll
    for (int j = 0; j < 4; ++j)
#pragma unroll
      for (int r = 0; r < 4; ++r) acc[i][j][r] = 0.f;

  gemm_core(qb + (bT + mb * 128) * (size_t)H_, H_,
            kb + (bT + nb * 128) * (size_t)H_, H_, H_,
            Alds, Blds, lane, wid, acc);

#pragma unroll
  for (int nt = 0; nt < 4; ++nt) {
    int gcol = nb * 128 + wn + nt * 16 + (lane & 15);
#pragma unroll
    for (int mt = 0; mt < 4; ++mt) {
      int grow = mb * 128 + wm + mt * 16 + (lane >> 4) * 4;
#pragma unroll
      for (int r = 0; r < 4; ++r)
        S[(bT + grow + r) * (size_t)T_ + gcol] = f2bf(acc[mt][nt][r] * 0.03125f);
    }
  }
}

// ---------- in-place causal row softmax: S(bf16 scores) -> P(bf16 probs) ----------
__global__ __launch_bounds__(256)
void smax_kernel(unsigned short* __restrict__ S) {
  int id = blockIdx.x;
  int b = id & 7, rb = id >> 3;                 // rb 0..511
  int w = threadIdx.x >> 6, lane = threadIdx.x & 63;
  int row = rb * 4 + w;
  unsigned short* rp = S + ((size_t)b * T_ + row) * T_;

  bf16x8 d[4];
#pragma unroll
  for (int j = 0; j < 4; ++j)
    d[j] = *(const bf16x8*)(rp + j * 512 + lane * 8);

  float v[32];
  float mx = -1e30f;
#pragma unroll
  for (int j = 0; j < 4; ++j)
#pragma unroll
    for (int e = 0; e < 8; ++e) {
      int col = j * 512 + lane * 8 + e;
      float f = bf2f((unsigned short)d[j][e]);
      f = (col <= row) ? f : -1e30f;
      v[j * 8 + e] = f;
      mx = fmaxf(mx, f);
    }
#pragma unroll
  for (int msk = 1; msk <= 32; msk <<= 1) mx = fmaxf(mx, __shfl_xor(mx, msk));

  float s = 0.f;
#pragma unroll
  for (int i = 0; i < 32; ++i) {
    v[i] = __expf(v[i] - mx);                   // masked: exp(-1e30 - mx) underflows to 0
    s += v[i];
  }
#pragma unroll
  for (int msk = 1; msk <= 32; msk <<= 1) s += __shfl_xor(s, msk);
  float inv = 1.0f / s;

#pragma unroll
  for (int j = 0; j < 4; ++j) {
    bf16x8 o;
#pragma unroll
    for (int e = 0; e < 8; ++e) o[e] = (short)f2bf(v[j * 8 + e] * inv);
    *(bf16x8*)(rp + j * 512 + lane * 8) = o;
  }
}

// ---------- O = P V, causal (K-range = (mb+1)*128), fp32 out ----------
__global__ __launch_bounds__(256)
void pv_kernel(const unsigned short* __restrict__ P, const unsigned short* __restrict__ vT,
               float* __restrict__ out) {
  __shared__ short Alds[128 * 64];
  __shared__ short Blds[128 * 64];
  int id = blockIdx.x;
  int b = id & 7, u = id >> 3;
  int mb = 15 - (u >> 3);                  // biggest K-range first (load balance)
  int nb = u & 7;                          // d-block 0..7
  const size_t bT = (size_t)b * T_;
  int tid = threadIdx.x, lane = tid & 63, wid = tid >> 6;
  int wm = (wid >> 1) * 64, wn = (wid & 1) * 64;

  f32x4 acc[4][4];
#pragma unroll
  for (int i = 0; i < 4; ++i)
#pragma unroll
    for (int j = 0; j < 4; ++j)
#pragma unroll
      for (int r = 0; r < 4; ++r) acc[i][j][r] = 0.f;

  gemm_core(P + (bT + mb * 128) * (size_t)T_, T_,
            vT + (size_t)(nb * 128) * M_ + bT, M_,
            (mb + 1) * 128, Alds, Blds, lane, wid, acc);

#pragma unroll
  for (int nt = 0; nt < 4; ++nt) {
    int gcol = nb * 128 + wn + nt * 16 + (lane & 15);
#pragma unroll
    for (int mt = 0; mt < 4; ++mt) {
      int grow = mb * 128 + wm + mt * 16 + (lane >> 4) * 4;
#pragma unroll
      for (int r = 0; r < 4; ++r)
        out[(bT + grow + r) * (size_t)H_ + gcol] = acc[mt][nt][r];
    }
  }
}

extern "C" void kernel_launch(void* const* d_in, const int* in_sizes, int n_in,
                              void* d_out, int out_size, void* d_ws, size_t ws_size,
                              hipStream_t stream) {
  const float* x  = (const float*)d_in[0];
  const float* Wq = (const float*)d_in[1];
  const float* bq = (const float*)d_in[2];
  const float* Wk = (const float*)d_in[3];
  const float* bk = (const float*)d_in[4];
  const float* Wv = (const float*)d_in[5];
  const float* bv = (const float*)d_in[6];
  float* out = (float*)d_out;

  unsigned short* ws = (unsigned short*)d_ws;
  unsigned short* xb  = ws;                              // M x E bf16      (32MB)
  unsigned short* wqT = xb  + (size_t)M_ * E_;           // H x E bf16
  unsigned short* wkT = wqT + (size_t)E_ * H_;
  unsigned short* wvT = wkT + (size_t)E_ * H_;
  unsigned short* qb  = wvT + (size_t)E_ * H_;           // M x H bf16      (32MB)
  unsigned short* kbp = qb  + (size_t)M_ * H_;           // M x H bf16
  unsigned short* vTp = kbp + (size_t)M_ * H_;           // H x M bf16 (V transposed)
  unsigned short* Sp  = vTp + (size_t)M_ * H_;           // B x T x T bf16  (67MB) S, then P in-place

  conv_x_kernel<<<(M_ * E_ / 8 + 255) / 256, 256, 0, stream>>>(x, xb, M_ * E_ / 8);
  conv_wT_kernel<<<dim3(32, 32, 3), 256, 0, stream>>>(Wq, Wk, Wv, wqT, wkT, wvT);
  gemm_qkv256_kernel<<<dim3(64, 12), 512, 0, stream>>>(xb, wqT, wkT, wvT, bq, bk, bv, qb, kbp, vTp);
  sgemm_kernel<<<dim3(136 * 8), 256, 0, stream>>>(qb, kbp, Sp);
  smax_kernel<<<dim3(512 * 8), 256, 0, stream>>>(Sp);
  pv_kernel<<<dim3(128 * 8), 256, 0, stream>>>(Sp, vTp, out);
}